// Round 1
// baseline (390.259 us; speedup 1.0000x reference)
//
#include <hip/hip_runtime.h>

typedef float f32x4 __attribute__((ext_vector_type(4)));
typedef float f32x2 __attribute__((ext_vector_type(2)));
typedef unsigned int u32x2 __attribute__((ext_vector_type(2)));
typedef __bf16 bf16x8 __attribute__((ext_vector_type(8)));

struct U8 { unsigned short s[8]; };
static_assert(sizeof(bf16x8) == 16, "bf16x8 must be 16B");
static_assert(sizeof(U8) == 16, "U8 must be 16B");

#define NB 4096
#define NT 64
#define FD 64
#define HD 128
#define BTF (NB * NT * FD)   // 16777216

__device__ __forceinline__ unsigned short f2bf(float x) {
  unsigned int u = __builtin_bit_cast(unsigned int, x);
  u += 0x7fffu + ((u >> 16) & 1u);       // round-to-nearest-even
  return (unsigned short)(u >> 16);
}

__device__ __forceinline__ f32x4 mfma16(bf16x8 a, bf16x8 b, f32x4 c) {
  return __builtin_amdgcn_mfma_f32_16x16x32_bf16(a, b, c, 0, 0, 0);
}

// Load 8 consecutive f32 of one W row -> bf16x8 B-fragment piece
__device__ __forceinline__ bf16x8 loadW8(const float* __restrict__ row, int k0) {
  f32x4 a = *(const f32x4*)(row + k0);
  f32x4 b = *(const f32x4*)(row + k0 + 4);
  U8 u;
#pragma unroll
  for (int j = 0; j < 4; ++j) { u.s[j] = f2bf(a[j]); u.s[4 + j] = f2bf(b[j]); }
  return __builtin_bit_cast(bf16x8, u);
}

// Same, but zero the diagonal element (for W_feat with zeroed diag)
__device__ __forceinline__ bf16x8 loadW8zd(const float* __restrict__ row, int k0, int col) {
  f32x4 a = *(const f32x4*)(row + k0);
  f32x4 b = *(const f32x4*)(row + k0 + 4);
  U8 u;
#pragma unroll
  for (int j = 0; j < 4; ++j) {
    u.s[j]     = (k0 + j     == col) ? (unsigned short)0 : f2bf(a[j]);
    u.s[4 + j] = (k0 + 4 + j == col) ? (unsigned short)0 : f2bf(b[j]);
  }
  return __builtin_bit_cast(bf16x8, u);
}

__device__ __forceinline__ float sigm(float x) { return 1.f / (1.f + __expf(-x)); }
__device__ __forceinline__ float tanh_fast(float x) { return 1.f - 2.f / (__expf(2.f * x) + 1.f); }

__global__ __launch_bounds__(512, 2) void rits_main_kernel(
    const float* __restrict__ values, const float* __restrict__ masks,
    const float* __restrict__ deltas,
    const float* __restrict__ W_dh, const float* __restrict__ b_dh,
    const float* __restrict__ W_dx, const float* __restrict__ b_dx,
    const float* __restrict__ W_hist, const float* __restrict__ b_hist,
    const float* __restrict__ W_feat, const float* __restrict__ b_feat,
    const float* __restrict__ W_comb, const float* __restrict__ b_comb,
    const float* __restrict__ W_ih, const float* __restrict__ b_ih,
    const float* __restrict__ W_hh, const float* __restrict__ b_hh,
    float* __restrict__ out_imp, float* __restrict__ out_est,
    float* __restrict__ out_h, float* __restrict__ loss_ws) {
  const int tid = threadIdx.x;
  const int w = tid >> 6;          // wave 0..7
  const int l = tid & 63;          // lane
  const int rA = l & 15;           // MFMA row (A) / col (C/D) index
  const int kg = l >> 4;           // k-group 0..3
  const int wg = blockIdx.x;
  const int b0 = wg * 16;

  // f32 tiles padded to 68/132/516 cols to break store bank conflicts
  __shared__ float sX[16][68], sM[16][68], sD[16][68];
  __shared__ float sH[16][132], sC[16][132];
  __shared__ float sXh[16][68], sZh[16][68], sAl[16][68], sCh[16][68];
  __shared__ float sGates[16][516];
  __shared__ unsigned short sHb[16][136];                 // h (post-decay) bf16, K=128
  __shared__ unsigned short sMb[16][72], sDb[16][72];     // m, d bf16, K=64
  __shared__ unsigned short sGxb[16][72], sXcb[16][72], sCcb[16][72];
  __shared__ float sBdh[128], sBdx[64], sBhist[64], sBfeat[64], sBcomb[64], sWdx[64];
  __shared__ float sBg[512];
  __shared__ float sLoss[8][4];

  // ---- one-time init: biases to LDS, h=c=0, weights -> register fragments ----
  if (tid < 128) sBdh[tid] = b_dh[tid];
  if (tid < 64) {
    sBdx[tid] = b_dx[tid];
    sBhist[tid] = b_hist[tid];
    sBfeat[tid] = b_feat[tid];
    sBcomb[tid] = b_comb[tid];
    sWdx[tid] = W_dx[tid * 65];   // diagonal of W_dx
  }
  sBg[tid] = b_ih[tid] + b_hh[tid];   // tid covers 0..511
  {
    int r = tid >> 5, c0 = (tid & 31) * 4;
    f32x4 z = {0.f, 0.f, 0.f, 0.f};
    *(f32x4*)&sH[r][c0] = z;
    *(f32x4*)&sC[r][c0] = z;
  }

  // gate weights: wave w owns gate cols [w*64, w*64+64) = 4 n-tiles x 8 k-steps
  bf16x8 wgf[4][8];
#pragma unroll
  for (int j = 0; j < 4; ++j) {
    int col = w * 64 + j * 16 + rA;
#pragma unroll
    for (int kk = 0; kk < 4; ++kk) wgf[j][kk] = loadW8(W_ih + (size_t)col * 128, kk * 32 + kg * 8);
#pragma unroll
    for (int kk = 0; kk < 4; ++kk) wgf[j][4 + kk] = loadW8(W_hh + (size_t)col * 128, kk * 32 + kg * 8);
  }
  bf16x8 wdhf[2];
  {
    int col = w * 16 + rA;   // N=128 across 8 waves
#pragma unroll
    for (int kk = 0; kk < 2; ++kk) wdhf[kk] = loadW8(W_dh + (size_t)col * 64, kk * 32 + kg * 8);
  }
  // wsm: waves 0-3: [0..3]=W_hist(kk), [4..5]=W_feat(kk); waves 4-7: [0..3]=W_comb(kk)
  bf16x8 wsm[6];
  if (w < 4) {
    int col = w * 16 + rA;
#pragma unroll
    for (int kk = 0; kk < 4; ++kk) wsm[kk] = loadW8(W_hist + (size_t)col * 128, kk * 32 + kg * 8);
#pragma unroll
    for (int kk = 0; kk < 2; ++kk) wsm[4 + kk] = loadW8zd(W_feat + (size_t)col * 64, kk * 32 + kg * 8, col);
  } else {
    int col = (w - 4) * 16 + rA;
#pragma unroll
    for (int kk = 0; kk < 4; ++kk) wsm[kk] = loadW8(W_comb + (size_t)col * 128, kk * 32 + kg * 8);
#pragma unroll
    for (int kk = 0; kk < 2; ++kk) { U8 z = {}; wsm[4 + kk] = __builtin_bit_cast(bf16x8, z); }
  }
  __syncthreads();

  for (int t = 0; t < NT; ++t) {
    // ---- P0: stage x, m, d tiles (f32 + bf16 copies of m, d) ----
    if (tid < 256) {
      int r = tid >> 4, q = tid & 15;
      f32x4 v = *(const f32x4*)&values[(size_t)(b0 + r) * 4096 + t * 64 + q * 4];
      *(f32x4*)&sX[r][q * 4] = v;
    } else {
      int r = (tid - 256) >> 4, q = (tid - 256) & 15;
      f32x4 v = *(const f32x4*)&masks[(size_t)(b0 + r) * 4096 + t * 64 + q * 4];
      *(f32x4*)&sM[r][q * 4] = v;
      u32x2 p;
      p[0] = (unsigned int)f2bf(v[0]) | ((unsigned int)f2bf(v[1]) << 16);
      p[1] = (unsigned int)f2bf(v[2]) | ((unsigned int)f2bf(v[3]) << 16);
      *(u32x2*)&sMb[r][q * 4] = p;
    }
    if (tid < 256) {
      int r = tid >> 4, q = tid & 15;
      f32x4 v = *(const f32x4*)&deltas[(size_t)(b0 + r) * 4096 + t * 64 + q * 4];
      *(f32x4*)&sD[r][q * 4] = v;
      u32x2 p;
      p[0] = (unsigned int)f2bf(v[0]) | ((unsigned int)f2bf(v[1]) << 16);
      p[1] = (unsigned int)f2bf(v[2]) | ((unsigned int)f2bf(v[3]) << 16);
      *(u32x2*)&sDb[r][q * 4] = p;
    }
    __syncthreads();

    // ---- P1: gamma_h = exp(-relu(d @ W_dh^T + b_dh)); h *= gamma_h ----
    {
      f32x4 acc = {0.f, 0.f, 0.f, 0.f};
#pragma unroll
      for (int kk = 0; kk < 2; ++kk) {
        bf16x8 a = *(const bf16x8*)&sDb[rA][kk * 32 + kg * 8];
        acc = mfma16(a, wdhf[kk], acc);
      }
      int col = w * 16 + rA;
#pragma unroll
      for (int i = 0; i < 4; ++i) {
        int row = kg * 4 + i;
        float g = __expf(-fmaxf(acc[i] + sBdh[col], 0.f));
        float hv = sH[row][col] * g;
        sH[row][col] = hv;
        sHb[row][col] = f2bf(hv);
      }
    }
    // P1b: gamma_x (diag decay), bf16 tile for alpha GEMM
    {
      int e = tid * 2, r = e >> 6, f0 = e & 63;
      float g0 = __expf(-fmaxf(sD[r][f0] * sWdx[f0] + sBdx[f0], 0.f));
      float g1 = __expf(-fmaxf(sD[r][f0 + 1] * sWdx[f0 + 1] + sBdx[f0 + 1], 0.f));
      *(unsigned int*)&sGxb[r][f0] = (unsigned int)f2bf(g0) | ((unsigned int)f2bf(g1) << 16);
    }
    __syncthreads();

    // ---- P2: waves 0-3: x_h = h @ W_hist^T + b_hist (and x_c);  waves 4-7: alpha ----
    if (w < 4) {
      f32x4 acc = {0.f, 0.f, 0.f, 0.f};
#pragma unroll
      for (int kk = 0; kk < 4; ++kk) {
        bf16x8 a = *(const bf16x8*)&sHb[rA][kk * 32 + kg * 8];
        acc = mfma16(a, wsm[kk], acc);
      }
      int col = w * 16 + rA;
#pragma unroll
      for (int i = 0; i < 4; ++i) {
        int row = kg * 4 + i;
        float xh = acc[i] + sBhist[col];
        sXh[row][col] = xh;
        float mm = sM[row][col], xx = sX[row][col];
        float xc = mm * xx + (1.f - mm) * xh;
        sXcb[row][col] = f2bf(xc);
      }
    } else {
      f32x4 acc = {0.f, 0.f, 0.f, 0.f};
#pragma unroll
      for (int kk = 0; kk < 2; ++kk) {
        bf16x8 a = *(const bf16x8*)&sGxb[rA][kk * 32 + kg * 8];
        acc = mfma16(a, wsm[kk], acc);
      }
#pragma unroll
      for (int kk = 0; kk < 2; ++kk) {
        bf16x8 a = *(const bf16x8*)&sMb[rA][kk * 32 + kg * 8];
        acc = mfma16(a, wsm[2 + kk], acc);
      }
      int col = (w - 4) * 16 + rA;
#pragma unroll
      for (int i = 0; i < 4; ++i) {
        int row = kg * 4 + i;
        sAl[row][col] = sigm(acc[i] + sBcomb[col]);
      }
    }
    __syncthreads();

    // ---- P3: waves 0-3: z_h = x_c @ Wfeat_od^T + b_feat; c_h = alpha*z_h+(1-alpha)*x_h ----
    if (w < 4) {
      f32x4 acc = {0.f, 0.f, 0.f, 0.f};
#pragma unroll
      for (int kk = 0; kk < 2; ++kk) {
        bf16x8 a = *(const bf16x8*)&sXcb[rA][kk * 32 + kg * 8];
        acc = mfma16(a, wsm[4 + kk], acc);
      }
      int col = w * 16 + rA;
#pragma unroll
      for (int i = 0; i < 4; ++i) {
        int row = kg * 4 + i;
        float zh = acc[i] + sBfeat[col];
        sZh[row][col] = zh;
        float al = sAl[row][col];
        sCh[row][col] = al * zh + (1.f - al) * sXh[row][col];
      }
    }
    __syncthreads();

    // ---- P4: outputs (est/imputed), c_c bf16, loss partials ----
    float n1, n2, n3, den;
    {
      int e = tid * 2, r = e >> 6, f0 = e & 63;
      float x0 = sX[r][f0], x1 = sX[r][f0 + 1];
      float m0 = sM[r][f0], m1 = sM[r][f0 + 1];
      float ch0 = sCh[r][f0], ch1 = sCh[r][f0 + 1];
      float xh0 = sXh[r][f0], xh1 = sXh[r][f0 + 1];
      float zh0 = sZh[r][f0], zh1 = sZh[r][f0 + 1];
      float cc0 = m0 * x0 + (1.f - m0) * ch0;
      float cc1 = m1 * x1 + (1.f - m1) * ch1;
      size_t go = (size_t)(b0 + r) * 4096 + t * 64 + f0;
      f32x2 e2; e2[0] = ch0; e2[1] = ch1;
      f32x2 i2; i2[0] = cc0; i2[1] = cc1;
      *(f32x2*)&out_est[go] = e2;
      *(f32x2*)&out_imp[go] = i2;
      *(unsigned int*)&sCcb[r][f0] = (unsigned int)f2bf(cc0) | ((unsigned int)f2bf(cc1) << 16);
      n1 = fabsf(xh0 - x0) * m0 + fabsf(xh1 - x1) * m1;
      n2 = fabsf(zh0 - x0) * m0 + fabsf(zh1 - x1) * m1;
      n3 = fabsf(ch0 - x0) * m0 + fabsf(ch1 - x1) * m1;
      den = m0 + m1;
    }
#pragma unroll
    for (int off = 32; off > 0; off >>= 1) {
      n1 += __shfl_down(n1, off);
      n2 += __shfl_down(n2, off);
      n3 += __shfl_down(n3, off);
      den += __shfl_down(den, off);
    }
    if (l == 0) { sLoss[w][0] = n1; sLoss[w][1] = n2; sLoss[w][2] = n3; sLoss[w][3] = den; }
    __syncthreads();
    if (tid < 4) {
      float s = 0.f;
#pragma unroll
      for (int q = 0; q < 8; ++q) s += sLoss[q][tid];
      loss_ws[((size_t)t * 256 + wg) * 4 + tid] = s;
    }

    // ---- P5: gates = [c_c|m] @ W_ih^T + h @ W_hh^T + (b_ih+b_hh) ----
    {
      f32x4 acc[4];
#pragma unroll
      for (int j = 0; j < 4; ++j) { f32x4 z = {0.f, 0.f, 0.f, 0.f}; acc[j] = z; }
#pragma unroll
      for (int kk = 0; kk < 8; ++kk) {
        bf16x8 a;
        if (kk < 2)      a = *(const bf16x8*)&sCcb[rA][kk * 32 + kg * 8];
        else if (kk < 4) a = *(const bf16x8*)&sMb[rA][(kk - 2) * 32 + kg * 8];
        else             a = *(const bf16x8*)&sHb[rA][(kk - 4) * 32 + kg * 8];
#pragma unroll
        for (int j = 0; j < 4; ++j) acc[j] = mfma16(a, wgf[j][kk], acc[j]);
      }
#pragma unroll
      for (int j = 0; j < 4; ++j) {
        int col = w * 64 + j * 16 + rA;
#pragma unroll
        for (int i = 0; i < 4; ++i) sGates[kg * 4 + i][col] = acc[j][i] + sBg[col];
      }
    }
    __syncthreads();

    // ---- P6: LSTM cell update ----
    {
      int r = tid >> 5, hc0 = (tid & 31) * 4;
      f32x4 gi = *(const f32x4*)&sGates[r][hc0];
      f32x4 gf = *(const f32x4*)&sGates[r][128 + hc0];
      f32x4 gg = *(const f32x4*)&sGates[r][256 + hc0];
      f32x4 go = *(const f32x4*)&sGates[r][384 + hc0];
      f32x4 co = *(const f32x4*)&sC[r][hc0];
      f32x4 cn, hn;
#pragma unroll
      for (int u = 0; u < 4; ++u) {
        float ii = sigm(gi[u]), ff = sigm(gf[u]);
        float g_ = tanh_fast(gg[u]), oo = sigm(go[u]);
        float c_ = ff * co[u] + ii * g_;
        cn[u] = c_;
        hn[u] = oo * tanh_fast(c_);
      }
      *(f32x4*)&sC[r][hc0] = cn;
      *(f32x4*)&sH[r][hc0] = hn;
    }
    __syncthreads();
  }

  // ---- final h output ----
  {
    int r = tid >> 5, hc0 = (tid & 31) * 4;
    *(f32x4*)&out_h[(size_t)(b0 + r) * 128 + hc0] = *(const f32x4*)&sH[r][hc0];
  }
}

__global__ void rits_loss_kernel(const float* __restrict__ ws, float* __restrict__ out_loss) {
  int tid = threadIdx.x;  // 64 threads = 1 wave
  float n1 = 0.f, n2 = 0.f, n3 = 0.f, den = 0.f;
  for (int g = 0; g < 256; ++g) {
    const float* p = &ws[((size_t)tid * 256 + g) * 4];
    n1 += p[0]; n2 += p[1]; n3 += p[2]; den += p[3];
  }
  float lt = (n1 + n2 + n3) / (den + 1e-12f);
#pragma unroll
  for (int off = 32; off > 0; off >>= 1) lt += __shfl_down(lt, off);
  if (tid == 0) out_loss[0] = lt / 192.f;   // / (T * 3)
}

extern "C" void kernel_launch(void* const* d_in, const int* in_sizes, int n_in,
                              void* d_out, int out_size, void* d_ws, size_t ws_size,
                              hipStream_t stream) {
  const float* values = (const float*)d_in[0];
  const float* masks  = (const float*)d_in[1];
  const float* deltas = (const float*)d_in[2];
  const float* W_dh   = (const float*)d_in[3];
  const float* b_dh   = (const float*)d_in[4];
  const float* W_dx   = (const float*)d_in[5];
  const float* b_dx   = (const float*)d_in[6];
  const float* W_hist = (const float*)d_in[7];
  const float* b_hist = (const float*)d_in[8];
  const float* W_feat = (const float*)d_in[9];
  const float* b_feat = (const float*)d_in[10];
  const float* W_comb = (const float*)d_in[11];
  const float* b_comb = (const float*)d_in[12];
  const float* W_ih   = (const float*)d_in[13];
  const float* b_ih   = (const float*)d_in[14];
  const float* W_hh   = (const float*)d_in[15];
  const float* b_hh   = (const float*)d_in[16];

  float* out = (float*)d_out;
  float* out_imp = out;                       // [B,T,F]
  float* out_est = out + (size_t)BTF;         // [B,T,F]
  float* out_h   = out + (size_t)2 * BTF;     // [B,H]
  float* out_ls  = out + (size_t)2 * BTF + (size_t)NB * HD;  // scalar
  float* loss_ws = (float*)d_ws;              // [T][256 wg][4]

  rits_main_kernel<<<256, 512, 0, stream>>>(
      values, masks, deltas, W_dh, b_dh, W_dx, b_dx, W_hist, b_hist,
      W_feat, b_feat, W_comb, b_comb, W_ih, b_ih, W_hh, b_hh,
      out_imp, out_est, out_h, loss_ws);
  rits_loss_kernel<<<1, 64, 0, stream>>>(loss_ws, out_ls);
}